// Round 2
// 242.712 us; speedup vs baseline: 1.0824x; 1.0824x over previous
//
#include <hip/hip_runtime.h>

#define B_ 4
#define S_ 2048
#define C_ 512
#define H_ 8
#define D_ 64
#define M_ 8192   // B_*S_

typedef short s8v __attribute__((ext_vector_type(8)));   // 8 bf16 (4 VGPRs)
typedef short s4v __attribute__((ext_vector_type(4)));   // 4 bf16 (2 VGPRs)
typedef float f4v __attribute__((ext_vector_type(4)));   // MFMA C/D
typedef unsigned short u16;
typedef unsigned int u32;

__device__ __forceinline__ u16 f2b(float f) {
    u32 u = __builtin_bit_cast(u32, f);
    u = u + 0x7fffu + ((u >> 16) & 1u);
    return (u16)(u >> 16);
}

__device__ __forceinline__ void b2f8(const s8v v, float* f) {
    #pragma unroll
    for (int k = 0; k < 8; ++k)
        f[k] = __builtin_bit_cast(float, (u32)(u16)v[k] << 16);
}

// async 16B global->LDS; lds dest is wave-uniform base, lane i lands at +16*i
__device__ __forceinline__ void gl2lds16(const void* g, void* l) {
    __builtin_amdgcn_global_load_lds(
        (const __attribute__((address_space(1))) void*)g,
        (__attribute__((address_space(3))) void*)l, 16, 0, 0);
}

// ---------------------------------------------------------------------------
// Combined prep: blocks [0,4096) convert x fp32->bf16; blocks [4096,5632)
// transpose+convert the 6 weight matrices (256 blocks each).
// ---------------------------------------------------------------------------
__global__ __launch_bounds__(256) void prep_k(const float* __restrict__ x,
                                              u16* __restrict__ xb,
                                              const float* __restrict__ s0,
                                              const float* __restrict__ s1,
                                              const float* __restrict__ s2,
                                              const float* __restrict__ s3,
                                              const float* __restrict__ s4,
                                              const float* __restrict__ s5,
                                              u16* __restrict__ d0,
                                              u16* __restrict__ d1,
                                              u16* __restrict__ d2,
                                              u16* __restrict__ d3,
                                              u16* __restrict__ d4,
                                              u16* __restrict__ d5)
{
    __shared__ float t[32][33];
    const int bx = blockIdx.x;
    if (bx < 4096) {
        const int i = (bx * 256 + (int)threadIdx.x) * 4;
        const float4 v = *(const float4*)&x[i];
        ushort4 o;
        o.x = f2b(v.x); o.y = f2b(v.y); o.z = f2b(v.z); o.w = f2b(v.w);
        *(ushort4*)&xb[i] = o;
        return;
    }
    const int tb = bx - 4096;
    const int z = tb >> 8, rem = tb & 255;
    const float* W; u16* Wt;
    switch (z) {
        case 0: W = s0; Wt = d0; break;
        case 1: W = s1; Wt = d1; break;
        case 2: W = s2; Wt = d2; break;
        case 3: W = s3; Wt = d3; break;
        case 4: W = s4; Wt = d4; break;
        default: W = s5; Wt = d5; break;
    }
    const int tx = threadIdx.x & 31, ty = threadIdx.x >> 5;
    const int n0 = (rem & 15) * 32, k0 = (rem >> 4) * 32;
    #pragma unroll
    for (int i = 0; i < 4; ++i)
        t[ty + i * 8][tx] = W[(size_t)(k0 + ty + i * 8) * C_ + n0 + tx];
    __syncthreads();
    #pragma unroll
    for (int i = 0; i < 4; ++i)
        Wt[(size_t)(n0 + ty + i * 8) * C_ + k0 + tx] = f2b(t[tx][ty + i * 8]);
}

// ---------------------------------------------------------------------------
// bf16 MFMA GEMM, 128x64 tile, BK=64, double-buffered, XOR-swizzled LDS
// (swizzle applied on the pre-swizzled global source since global_load_lds
// writes linearly). 4 waves in 2x2; wave tile 64x32 (4x2 16x16 frags).
// grid (M/128, N/64): linear id = x + gridDim.x*y -> all N-tiles of one
// A-panel share x&7 -> same XCD -> A-panel L2 reuse.
// ---------------------------------------------------------------------------
template <bool OB>
__global__ __launch_bounds__(256) void gemm_k(const u16* __restrict__ A,
                                              const u16* __restrict__ Bt,
                                              const float* __restrict__ bias,
                                              void* __restrict__ outv)
{
    __shared__ u16 As[2][128][64];   // 16KB/buf
    __shared__ u16 Bs[2][64][64];    // 8KB/buf
    const int tid = threadIdx.x;
    const int lane = tid & 63, w = tid >> 6;
    const int q4 = lane >> 4, l16 = lane & 15;
    const int wr = w >> 1, wc = w & 1;
    const int bm = blockIdx.x * 128, bn = blockIdx.y * 64;
    const int sr8  = lane >> 3;                  // staging sub-row (0..7)
    const int scol = ((lane & 7) ^ sr8) * 8;     // pre-swizzled k-chunk (u16)

    f4v acc[4][2];
    #pragma unroll
    for (int i = 0; i < 4; ++i)
        #pragma unroll
        for (int j = 0; j < 2; ++j) acc[i][j] = (f4v){0.f, 0.f, 0.f, 0.f};

    const u16* Ab = A  + (size_t)bm * C_;
    const u16* Bb = Bt + (size_t)bn * C_;

    auto stage = [&](int bf, int kt) {
        const int k0 = kt * 64;
        #pragma unroll
        for (int t = 0; t < 4; ++t)
            gl2lds16(Ab + (size_t)(w * 32 + t * 8 + sr8) * C_ + k0 + scol,
                     (char*)As + bf * 16384 + (w * 32 + t * 8) * 128);
        #pragma unroll
        for (int t = 0; t < 2; ++t)
            gl2lds16(Bb + (size_t)(w * 16 + t * 8 + sr8) * C_ + k0 + scol,
                     (char*)Bs + bf * 8192 + (w * 16 + t * 8) * 128);
    };

    stage(0, 0);
    for (int kt = 0; kt < 8; ++kt) {
        __syncthreads();
        const int bf = kt & 1;
        if (kt < 7) stage(bf ^ 1, kt + 1);
        #pragma unroll
        for (int kk = 0; kk < 2; ++kk) {
            const int pc = ((kk * 4 + q4) ^ (l16 & 7)) * 8;  // phys chunk (u16)
            s8v a[4], b[2];
            #pragma unroll
            for (int i = 0; i < 4; ++i)
                a[i] = *(const s8v*)&As[bf][wr * 64 + i * 16 + l16][pc];
            #pragma unroll
            for (int j = 0; j < 2; ++j)
                b[j] = *(const s8v*)&Bs[bf][wc * 32 + j * 16 + l16][pc];
            #pragma unroll
            for (int i = 0; i < 4; ++i)
                #pragma unroll
                for (int j = 0; j < 2; ++j)
                    acc[i][j] = __builtin_amdgcn_mfma_f32_16x16x32_bf16(a[i], b[j], acc[i][j], 0, 0, 0);
        }
    }

    #pragma unroll
    for (int j = 0; j < 2; ++j) {
        const int n = bn + wc * 32 + j * 16 + l16;
        const float bj = bias ? bias[n] : 0.0f;
        #pragma unroll
        for (int i = 0; i < 4; ++i) {
            const int m = bm + wr * 64 + i * 16 + q4 * 4;
            #pragma unroll
            for (int reg = 0; reg < 4; ++reg) {
                const float vv = acc[i][j][reg] + bj;
                if constexpr (OB) ((u16*)outv)[(size_t)(m + reg) * C_ + n] = f2b(vv);
                else              ((float*)outv)[(size_t)(m + reg) * C_ + n] = vv;
            }
        }
    }
}

// ---------------------------------------------------------------------------
// Fused QKV projection, 128x64 tiles, grid (64, 24) = 1536 blocks.
// which = blockIdx.y>>3 selects {Wq,Wk,Wv}. K written with k-group XOR
// swizzle; V written TRANSPOSED + XOR-swizzled into Vt[b,h,d,s].
// Swizzle formulas depend only on m&15 = q4*4+reg and n -> unchanged from
// the 64x64 version.
// ---------------------------------------------------------------------------
__global__ __launch_bounds__(256) void qkv_k(const u16* __restrict__ A,
                                             const u16* __restrict__ Wq,
                                             const u16* __restrict__ Wk,
                                             const u16* __restrict__ Wv,
                                             u16* __restrict__ oq,
                                             u16* __restrict__ ok,
                                             u16* __restrict__ ovt)
{
    __shared__ u16 As[2][128][64];
    __shared__ u16 Bs[2][64][64];
    const int tid = threadIdx.x;
    const int lane = tid & 63, w = tid >> 6;
    const int q4 = lane >> 4, l16 = lane & 15;
    const int wr = w >> 1, wc = w & 1;
    const int nt = blockIdx.y, which = nt >> 3;
    const u16* Bt = which == 0 ? Wq : (which == 1 ? Wk : Wv);
    const int bm = blockIdx.x * 128, bn = (nt & 7) * 64;
    const int sr8  = lane >> 3;
    const int scol = ((lane & 7) ^ sr8) * 8;

    f4v acc[4][2];
    #pragma unroll
    for (int i = 0; i < 4; ++i)
        #pragma unroll
        for (int j = 0; j < 2; ++j) acc[i][j] = (f4v){0.f, 0.f, 0.f, 0.f};

    const u16* Ab = A  + (size_t)bm * C_;
    const u16* Bb = Bt + (size_t)bn * C_;

    auto stage = [&](int bf, int kt) {
        const int k0 = kt * 64;
        #pragma unroll
        for (int t = 0; t < 4; ++t)
            gl2lds16(Ab + (size_t)(w * 32 + t * 8 + sr8) * C_ + k0 + scol,
                     (char*)As + bf * 16384 + (w * 32 + t * 8) * 128);
        #pragma unroll
        for (int t = 0; t < 2; ++t)
            gl2lds16(Bb + (size_t)(w * 16 + t * 8 + sr8) * C_ + k0 + scol,
                     (char*)Bs + bf * 8192 + (w * 16 + t * 8) * 128);
    };

    stage(0, 0);
    for (int kt = 0; kt < 8; ++kt) {
        __syncthreads();
        const int bf = kt & 1;
        if (kt < 7) stage(bf ^ 1, kt + 1);
        #pragma unroll
        for (int kk = 0; kk < 2; ++kk) {
            const int pc = ((kk * 4 + q4) ^ (l16 & 7)) * 8;
            s8v a[4], b[2];
            #pragma unroll
            for (int i = 0; i < 4; ++i)
                a[i] = *(const s8v*)&As[bf][wr * 64 + i * 16 + l16][pc];
            #pragma unroll
            for (int j = 0; j < 2; ++j)
                b[j] = *(const s8v*)&Bs[bf][wc * 32 + j * 16 + l16][pc];
            #pragma unroll
            for (int i = 0; i < 4; ++i)
                #pragma unroll
                for (int j = 0; j < 2; ++j)
                    acc[i][j] = __builtin_amdgcn_mfma_f32_16x16x32_bf16(a[i], b[j], acc[i][j], 0, 0, 0);
        }
    }

    if (which == 0) {
        #pragma unroll
        for (int j = 0; j < 2; ++j) {
            const int n = bn + wc * 32 + j * 16 + l16;
            #pragma unroll
            for (int i = 0; i < 4; ++i) {
                const int m = bm + wr * 64 + i * 16 + q4 * 4;
                #pragma unroll
                for (int reg = 0; reg < 4; ++reg)
                    oq[(size_t)(m + reg) * C_ + n] = f2b(acc[i][j][reg]);
            }
        }
    } else if (which == 1) {
        #pragma unroll
        for (int j = 0; j < 2; ++j) {
            const int n = bn + wc * 32 + j * 16 + l16;
            const int nswz = (n & ~31) | ((((n >> 3) & 3) ^ q4) << 3) | (n & 7);
            #pragma unroll
            for (int i = 0; i < 4; ++i) {
                const int m = bm + wr * 64 + i * 16 + q4 * 4;
                #pragma unroll
                for (int reg = 0; reg < 4; ++reg)
                    ok[(size_t)(m + reg) * C_ + nswz] = f2b(acc[i][j][reg]);
            }
        }
    } else {
        const int bglob = bm >> 11;
        const int sbase = bm & (S_ - 1);
        #pragma unroll
        for (int j = 0; j < 2; ++j) {
            const int n = bn + wc * 32 + j * 16 + l16;
            const int h = n >> 6, d = n & 63;
            u16* vrow = ovt + ((size_t)(bglob * H_ + h) * D_ + d) * S_;
            const int xw = d & 7;
            #pragma unroll
            for (int i = 0; i < 4; ++i) {
                const int s = sbase + wr * 64 + i * 16 + q4 * 4;
                const int pg = ((s & 31) >> 2) ^ xw;
                s4v pv;
                #pragma unroll
                for (int reg = 0; reg < 4; ++reg) pv[reg] = (short)f2b(acc[i][j][reg]);
                *(s4v*)&vrow[(s & ~31) + (pg << 2)] = pv;
            }
        }
    }
}

// ---------------------------------------------------------------------------
// bf16-chain LayerNorm kernels. One wave per row, 4 rows/block.
// ---------------------------------------------------------------------------
__global__ __launch_bounds__(256) void ln2xb_k(const u16* __restrict__ in,
                                               const float* __restrict__ res,
                                               const float* __restrict__ w1,
                                               const float* __restrict__ b1,
                                               const float* __restrict__ w2,
                                               const float* __restrict__ b2,
                                               u16* __restrict__ out1,
                                               u16* __restrict__ out2)
{
    const int lane = threadIdx.x & 63;
    const int row  = blockIdx.x * 4 + (threadIdx.x >> 6);
    const size_t off = (size_t)row * C_ + lane * 8;
    float v[8];
    b2f8(*(const s8v*)&in[off], v);
    {
        const float4 r0 = *(const float4*)&res[off];
        const float4 r1 = *(const float4*)&res[off + 4];
        v[0] += r0.x; v[1] += r0.y; v[2] += r0.z; v[3] += r0.w;
        v[4] += r1.x; v[5] += r1.y; v[6] += r1.z; v[7] += r1.w;
    }
    float s = 0.f, ss = 0.f;
    #pragma unroll
    for (int k = 0; k < 8; ++k) { s += v[k]; ss += v[k] * v[k]; }
    #pragma unroll
    for (int o = 32; o >= 1; o >>= 1) { s += __shfl_xor(s, o); ss += __shfl_xor(ss, o); }
    float mean = s * (1.0f / C_);
    float rstd = rsqrtf(ss * (1.0f / C_) - mean * mean + 1e-5f);

    const float4 wA0 = *(const float4*)&w1[lane * 8];
    const float4 wA1 = *(const float4*)&w1[lane * 8 + 4];
    const float4 bA0 = *(const float4*)&b1[lane * 8];
    const float4 bA1 = *(const float4*)&b1[lane * 8 + 4];
    const float wA[8] = {wA0.x, wA0.y, wA0.z, wA0.w, wA1.x, wA1.y, wA1.z, wA1.w};
    const float bA[8] = {bA0.x, bA0.y, bA0.z, bA0.w, bA1.x, bA1.y, bA1.z, bA1.w};
    float y[8];
    s8v o1;
    #pragma unroll
    for (int k = 0; k < 8; ++k) {
        y[k] = (v[k] - mean) * rstd * wA[k] + bA[k];
        o1[k] = (short)f2b(y[k]);
    }
    *(s8v*)&out1[off] = o1;

    s = 0.f; ss = 0.f;
    #pragma unroll
    for (int k = 0; k < 8; ++k) { s += y[k]; ss += y[k] * y[k]; }
    #pragma unroll
    for (int o = 32; o >= 1; o >>= 1) { s += __shfl_xor(s, o); ss += __shfl_xor(ss, o); }
    mean = s * (1.0f / C_);
    rstd = rsqrtf(ss * (1.0f / C_) - mean * mean + 1e-5f);

    const float4 wB0 = *(const float4*)&w2[lane * 8];
    const float4 wB1 = *(const float4*)&w2[lane * 8 + 4];
    const float4 bB0 = *(const float4*)&b2[lane * 8];
    const float4 bB1 = *(const float4*)&b2[lane * 8 + 4];
    const float wB[8] = {wB0.x, wB0.y, wB0.z, wB0.w, wB1.x, wB1.y, wB1.z, wB1.w};
    const float bB[8] = {bB0.x, bB0.y, bB0.z, bB0.w, bB1.x, bB1.y, bB1.z, bB1.w};
    s8v o2;
    #pragma unroll
    for (int k = 0; k < 8; ++k)
        o2[k] = (short)f2b((y[k] - mean) * rstd * wB[k] + bB[k]);
    *(s8v*)&out2[off] = o2;
}

__global__ __launch_bounds__(256) void lnb_k(const u16* __restrict__ in,
                                             const float* __restrict__ w,
                                             const float* __restrict__ bb,
                                             u16* __restrict__ out)
{
    const int lane = threadIdx.x & 63;
    const int row  = blockIdx.x * 4 + (threadIdx.x >> 6);
    const size_t off = (size_t)row * C_ + lane * 8;
    float v[8];
    b2f8(*(const s8v*)&in[off], v);
    float s = 0.f, ss = 0.f;
    #pragma unroll
    for (int k = 0; k < 8; ++k) { s += v[k]; ss += v[k] * v[k]; }
    #pragma unroll
    for (int o = 32; o >= 1; o >>= 1) { s += __shfl_xor(s, o); ss += __shfl_xor(ss, o); }
    const float mean = s * (1.0f / C_);
    const float rstd = rsqrtf(ss * (1.0f / C_) - mean * mean + 1e-5f);
    const float4 w0 = *(const float4*)&w[lane * 8];
    const float4 w1 = *(const float4*)&w[lane * 8 + 4];
    const float4 b0 = *(const float4*)&bb[lane * 8];
    const float4 b1 = *(const float4*)&bb[lane * 8 + 4];
    const float wv[8] = {w0.x, w0.y, w0.z, w0.w, w1.x, w1.y, w1.z, w1.w};
    const float bv[8] = {b0.x, b0.y, b0.z, b0.w, b1.x, b1.y, b1.z, b1.w};
    s8v o;
    #pragma unroll
    for (int k = 0; k < 8; ++k)
        o[k] = (short)f2b((v[k] - mean) * rstd * wv[k] + bv[k]);
    *(s8v*)&out[off] = o;
}

__global__ __launch_bounds__(256) void lnfin_k(const u16* __restrict__ in,
                                               const u16* __restrict__ res,
                                               const float* __restrict__ w,
                                               const float* __restrict__ bb,
                                               float* __restrict__ out)
{
    const int lane = threadIdx.x & 63;
    const int row  = blockIdx.x * 4 + (threadIdx.x >> 6);
    const size_t off = (size_t)row * C_ + lane * 8;
    float v[8], r[8];
    b2f8(*(const s8v*)&in[off], v);
    b2f8(*(const s8v*)&res[off], r);
    #pragma unroll
    for (int k = 0; k < 8; ++k) v[k] += r[k];
    float s = 0.f, ss = 0.f;
    #pragma unroll
    for (int k = 0; k < 8; ++k) { s += v[k]; ss += v[k] * v[k]; }
    #pragma unroll
    for (int o = 32; o >= 1; o >>= 1) { s += __shfl_xor(s, o); ss += __shfl_xor(ss, o); }
    const float mean = s * (1.0f / C_);
    const float rstd = rsqrtf(ss * (1.0f / C_) - mean * mean + 1e-5f);
    const float4 w0 = *(const float4*)&w[lane * 8];
    const float4 w1 = *(const float4*)&w[lane * 8 + 4];
    const float4 b0 = *(const float4*)&bb[lane * 8];
    const float4 b1 = *(const float4*)&bb[lane * 8 + 4];
    const float wv[8] = {w0.x, w0.y, w0.z, w0.w, w1.x, w1.y, w1.z, w1.w};
    const float bv[8] = {b0.x, b0.y, b0.z, b0.w, b1.x, b1.y, b1.z, b1.w};
    float4 o0, o1;
    o0.x = (v[0] - mean) * rstd * wv[0] + bv[0];
    o0.y = (v[1] - mean) * rstd * wv[1] + bv[1];
    o0.z = (v[2] - mean) * rstd * wv[2] + bv[2];
    o0.w = (v[3] - mean) * rstd * wv[3] + bv[3];
    o1.x = (v[4] - mean) * rstd * wv[4] + bv[4];
    o1.y = (v[5] - mean) * rstd * wv[5] + bv[5];
    o1.z = (v[6] - mean) * rstd * wv[6] + bv[6];
    o1.w = (v[7] - mean) * rstd * wv[7] + bv[7];
    *(float4*)&out[off]     = o0;
    *(float4*)&out[off + 4] = o1;
}

// ---------------------------------------------------------------------------
// Causal flash attention, register-resident P. grid (32,H,B), 256 thr.
// LPT ordering: qb = 31 - blockIdx.x (heaviest blocks dispatch first ->
// scheduler backfills with light blocks, minimal tail).
// Diagonal tile peeled behind a uniform branch (non-diag path has no mask
// VALU ops). Transposed scores -> P in mfma_16x16x16 A-operand layout; PV
// from registers. Constant-max softmax (exact). K/V^T double-buffered via
// global_load_lds (both globally pre-swizzled).
// ---------------------------------------------------------------------------
__global__ __launch_bounds__(256) void attn_k(const u16* __restrict__ Q,
                                              const u16* __restrict__ K,
                                              const u16* __restrict__ Vt,
                                              u16* __restrict__ O)
{
    __shared__ u16 Ks[2][2][64][32];   // [buf][kh][key][k32] (k-group swizzled)
    __shared__ u16 Vs[2][2][64][32];   // [buf][keyhalf][d][key32] (swizzled)
    const int tid = threadIdx.x;
    const int lane = tid & 63, w = tid >> 6;
    const int q4 = lane >> 4, l16 = lane & 15;
    const int h = blockIdx.y, b = blockIdx.z;
    const int qb = 31 - (int)blockIdx.x;      // LPT: heavy first
    const size_t base  = ((size_t)b * S_) * C_ + h * D_;
    const size_t basev = ((size_t)(b * H_ + h)) * D_ * S_;
    const int lr = lane >> 2, lc = (lane & 3) * 8;
    const int kq = (q4 ^ ((l16 >> 2) & 3)) * 8;   // undo K k-group swizzle

    s8v qf[2];
    #pragma unroll
    for (int kh = 0; kh < 2; ++kh)
        qf[kh] = *(const s8v*)&Q[base + (size_t)(qb * 64 + w * 16 + l16) * C_ + kh * 32 + q4 * 8];

    #pragma unroll
    for (int r = 0; r < 2; ++r) {
        const int seg = r * 4 + w;
        const int row = (seg & 3) * 16 + lr;
        const int kh = seg >> 2;
        gl2lds16(K  + base  + (size_t)row * C_ + kh * 32 + lc, (char*)Ks + seg * 1024);
        gl2lds16(Vt + basev + (size_t)row * S_ + kh * 32 + lc, (char*)Vs + seg * 1024);
    }

    f4v o[4];
    float lp[4] = {0.f, 0.f, 0.f, 0.f};
    #pragma unroll
    for (int j = 0; j < 4; ++j) o[j] = (f4v){0.f, 0.f, 0.f, 0.f};

    const int qrow = w * 16 + l16;
    for (int kb = 0; kb <= qb; ++kb) {
        __syncthreads();
        const int buf = kb & 1;
        if (kb < qb) {
            const int nb = buf ^ 1, kn = kb + 1;
            #pragma unroll
            for (int r = 0; r < 2; ++r) {
                const int seg = r * 4 + w;
                const int row = (seg & 3) * 16 + lr;
                const int kh = seg >> 2;
                gl2lds16(K  + base  + (size_t)(kn * 64 + row) * C_ + kh * 32 + lc,
                         (char*)Ks + nb * 8192 + seg * 1024);
                gl2lds16(Vt + basev + (size_t)row * S_ + kn * 64 + kh * 32 + lc,
                         (char*)Vs + nb * 8192 + seg * 1024);
            }
        }

        f4v sc[4];
        #pragma unroll
        for (int j = 0; j < 4; ++j) sc[j] = (f4v){0.f, 0.f, 0.f, 0.f};
        #pragma unroll
        for (int kh = 0; kh < 2; ++kh) {
            #pragma unroll
            for (int j = 0; j < 4; ++j) {
                const s8v kf = *(const s8v*)&Ks[buf][kh][j * 16 + l16][kq];
                sc[j] = __builtin_amdgcn_mfma_f32_16x16x32_bf16(kf, qf[kh], sc[j], 0, 0, 0);
            }
        }

        s4v pa[4];
        if (kb == qb) {      // diagonal tile: masked path
            #pragma unroll
            for (int j = 0; j < 4; ++j) {
                float ps = 0.0f;
                #pragma unroll
                for (int reg = 0; reg < 4; ++reg) {
                    float t = fmaf(sc[j][reg], 0.18033688011112043f, -11.541560327111707f);
                    if ((j * 16 + q4 * 4 + reg) > qrow) t = -128.0f;
                    const float p = exp2f(t);
                    ps += p;
                    pa[j][reg] = (short)(__builtin_bit_cast(u32, p) >> 16);
                }
                lp[j] += ps;
            }
        } else {             // interior tile: no mask VALU
            #pragma unroll
            for (int j = 0; j < 4; ++j) {
                float ps = 0.0f;
                #pragma unroll
                for (int reg = 0; reg < 4; ++reg) {
                    const float p = exp2f(fmaf(sc[j][reg], 0.18033688011112043f,
                                               -11.541560327111707f));
                    ps += p;
                    pa[j][reg] = (short)(__builtin_bit_cast(u32, p) >> 16);
                }
                lp[j] += ps;
            }
        }

        #pragma unroll
        for (int c = 0; c < 4; ++c) {
            const int gh = (((c & 1) * 4 + q4) ^ (l16 & 7)) * 4;
            #pragma unroll
            for (int dj = 0; dj < 4; ++dj) {
                const s4v vb = *(const s4v*)&Vs[buf][c >> 1][dj * 16 + l16][gh];
                o[dj] = __builtin_amdgcn_mfma_f32_16x16x16bf16_1k(pa[c], vb, o[dj], 0, 0, 0);
            }
        }
    }

    float lt = (lp[0] + lp[1]) + (lp[2] + lp[3]);
    lt += __shfl_xor(lt, 16);
    lt += __shfl_xor(lt, 32);
    #pragma unroll
    for (int reg = 0; reg < 4; ++reg) {
        const float inv = 1.0f / __shfl(lt, q4 * 4 + reg);
        const size_t rowoff = base + (size_t)(qb * 64 + w * 16 + q4 * 4 + reg) * C_;
        #pragma unroll
        for (int dj = 0; dj < 4; ++dj)
            O[rowoff + dj * 16 + l16] = f2b(o[dj][reg] * inv);
    }
}

// ---------------------------------------------------------------------------
extern "C" void kernel_launch(void* const* d_in, const int* in_sizes, int n_in,
                              void* d_out, int out_size, void* d_ws, size_t ws_size,
                              hipStream_t stream)
{
    const float* x       = (const float*)d_in[0];
    const float* Wq      = (const float*)d_in[1];
    const float* Wk      = (const float*)d_in[2];
    const float* Wv      = (const float*)d_in[3];
    const float* Wo      = (const float*)d_in[4];
    const float* ln1_w   = (const float*)d_in[5];
    const float* ln1_b   = (const float*)d_in[6];
    const float* ffln1_w = (const float*)d_in[7];
    const float* ffln1_b = (const float*)d_in[8];
    const float* ff_w1   = (const float*)d_in[9];
    const float* ff_b1   = (const float*)d_in[10];
    const float* ffln2_w = (const float*)d_in[11];
    const float* ffln2_b = (const float*)d_in[12];
    const float* ff_w2   = (const float*)d_in[13];
    const float* ff_b2   = (const float*)d_in[14];
    const float* ln2_w   = (const float*)d_in[15];
    const float* ln2_b   = (const float*)d_in[16];
    float* out = (float*)d_out;

    const size_t MC = (size_t)M_ * C_;   // 4,194,304
    const size_t WW = (size_t)C_ * C_;
    u16* xb   = (u16*)d_ws;
    u16* WqT  = xb + MC;
    u16* WkT  = WqT + WW;
    u16* WvT  = WkT + WW;
    u16* WoT  = WvT + WW;
    u16* W1T  = WoT + WW;
    u16* W2T  = W1T + WW;
    u16* qbuf = W2T + WW;
    u16* kbuf = qbuf + MC;
    u16* vbuf = kbuf + MC;
    u16* vtbuf= vbuf + MC;
    u16*  abuf = xb;       // attn out; xb dead after qkv_k
    u16*  tf   = qbuf;     // bf16 chain intermediate (qbuf dead after attn)
    u16*  xln  = vbuf;     // bf16 x_ln (vbuf spare)

    const dim3 gg(M_ / 128, C_ / 64);    // (64, 8) = 512 gemm blocks, 2/CU
    const dim3 gq(M_ / 128, 24);         // fused QKV, 1536 blocks, 3/CU
    const dim3 ga(32, H_, B_);           // 1024 attn blocks (LPT-ordered)
    const int  gl = M_ / 4;

    prep_k<<<5632, 256, 0, stream>>>(x, xb, Wq, Wk, Wv, Wo, ff_w1, ff_w2,
                                     WqT, WkT, WvT, WoT, W1T, W2T);

    qkv_k<<<gq, 256, 0, stream>>>(xb, WqT, WkT, WvT, qbuf, kbuf, vtbuf);
    attn_k<<<ga, 256, 0, stream>>>(qbuf, kbuf, vtbuf, abuf);

    // t = a@Wo (bf16); xln = LN(t+x, ln1) bf16; xb = LN(xln, ffln1) bf16
    gemm_k<true><<<gg, 256, 0, stream>>>(abuf, WoT, nullptr, tf);
    ln2xb_k<<<gl, 256, 0, stream>>>(tf, x, ln1_w, ln1_b, ffln1_w, ffln1_b,
                                    xln, xb);
    // h1 = xb@W1 + b1 (bf16); xb = LN(h1, ffln2) bf16
    gemm_k<true><<<gg, 256, 0, stream>>>(xb, W1T, ff_b1, tf);
    lnb_k<<<gl, 256, 0, stream>>>(tf, ffln2_w, ffln2_b, xb);
    // h2 = xb@W2 + b2 (bf16); out = LN(h2 + xln, ln2) fp32
    gemm_k<true><<<gg, 256, 0, stream>>>(xb, W2T, ff_b2, tf);
    lnfin_k<<<gl, 256, 0, stream>>>(tf, xln, ln2_w, ln2_b, out);
}

// Round 4
// 228.475 us; speedup vs baseline: 1.1498x; 1.0623x over previous
//
#include <hip/hip_runtime.h>

#define B_ 4
#define S_ 2048
#define C_ 512
#define H_ 8
#define D_ 64
#define M_ 8192   // B_*S_

typedef short s8v __attribute__((ext_vector_type(8)));   // 8 bf16 (4 VGPRs)
typedef short s4v __attribute__((ext_vector_type(4)));   // 4 bf16 (2 VGPRs)
typedef float f4v __attribute__((ext_vector_type(4)));   // MFMA C/D
typedef unsigned short u16;
typedef unsigned int u32;

__device__ __forceinline__ u16 f2b(float f) {
    u32 u = __builtin_bit_cast(u32, f);
    u = u + 0x7fffu + ((u >> 16) & 1u);
    return (u16)(u >> 16);
}

__device__ __forceinline__ void b2f8(const s8v v, float* f) {
    #pragma unroll
    for (int k = 0; k < 8; ++k)
        f[k] = __builtin_bit_cast(float, (u32)(u16)v[k] << 16);
}

// async 16B global->LDS; lds dest is wave-uniform base, lane i lands at +16*i
__device__ __forceinline__ void gl2lds16(const void* g, void* l) {
    __builtin_amdgcn_global_load_lds(
        (const __attribute__((address_space(1))) void*)g,
        (__attribute__((address_space(3))) void*)l, 16, 0, 0);
}

// ---------------------------------------------------------------------------
// Combined prep: blocks [0,4096) convert x fp32->bf16; blocks [4096,5632)
// transpose+convert the 6 weight matrices (256 blocks each).
// ---------------------------------------------------------------------------
__global__ __launch_bounds__(256) void prep_k(const float* __restrict__ x,
                                              u16* __restrict__ xb,
                                              const float* __restrict__ s0,
                                              const float* __restrict__ s1,
                                              const float* __restrict__ s2,
                                              const float* __restrict__ s3,
                                              const float* __restrict__ s4,
                                              const float* __restrict__ s5,
                                              u16* __restrict__ d0,
                                              u16* __restrict__ d1,
                                              u16* __restrict__ d2,
                                              u16* __restrict__ d3,
                                              u16* __restrict__ d4,
                                              u16* __restrict__ d5)
{
    __shared__ float t[32][33];
    const int bx = blockIdx.x;
    if (bx < 4096) {
        const int i = (bx * 256 + (int)threadIdx.x) * 4;
        const float4 v = *(const float4*)&x[i];
        ushort4 o;
        o.x = f2b(v.x); o.y = f2b(v.y); o.z = f2b(v.z); o.w = f2b(v.w);
        *(ushort4*)&xb[i] = o;
        return;
    }
    const int tb = bx - 4096;
    const int z = tb >> 8, rem = tb & 255;
    const float* W; u16* Wt;
    switch (z) {
        case 0: W = s0; Wt = d0; break;
        case 1: W = s1; Wt = d1; break;
        case 2: W = s2; Wt = d2; break;
        case 3: W = s3; Wt = d3; break;
        case 4: W = s4; Wt = d4; break;
        default: W = s5; Wt = d5; break;
    }
    const int tx = threadIdx.x & 31, ty = threadIdx.x >> 5;
    const int n0 = (rem & 15) * 32, k0 = (rem >> 4) * 32;
    #pragma unroll
    for (int i = 0; i < 4; ++i)
        t[ty + i * 8][tx] = W[(size_t)(k0 + ty + i * 8) * C_ + n0 + tx];
    __syncthreads();
    #pragma unroll
    for (int i = 0; i < 4; ++i)
        Wt[(size_t)(n0 + ty + i * 8) * C_ + k0 + tx] = f2b(t[tx][ty + i * 8]);
}

// ---------------------------------------------------------------------------
// bf16 MFMA GEMM, 128x64 tile, BK=64, double-buffered, XOR-swizzled LDS
// (swizzle applied on the pre-swizzled global source since global_load_lds
// writes linearly). 4 waves in 2x2; wave tile 64x32 (4x2 16x16 frags).
// ---------------------------------------------------------------------------
template <bool OB>
__global__ __launch_bounds__(256) void gemm_k(const u16* __restrict__ A,
                                              const u16* __restrict__ Bt,
                                              const float* __restrict__ bias,
                                              void* __restrict__ outv)
{
    __shared__ u16 As[2][128][64];   // 16KB/buf
    __shared__ u16 Bs[2][64][64];    // 8KB/buf
    const int tid = threadIdx.x;
    const int lane = tid & 63, w = tid >> 6;
    const int q4 = lane >> 4, l16 = lane & 15;
    const int wr = w >> 1, wc = w & 1;
    const int bm = blockIdx.x * 128, bn = blockIdx.y * 64;
    const int sr8  = lane >> 3;                  // staging sub-row (0..7)
    const int scol = ((lane & 7) ^ sr8) * 8;     // pre-swizzled k-chunk (u16)

    f4v acc[4][2];
    #pragma unroll
    for (int i = 0; i < 4; ++i)
        #pragma unroll
        for (int j = 0; j < 2; ++j) acc[i][j] = (f4v){0.f, 0.f, 0.f, 0.f};

    const u16* Ab = A  + (size_t)bm * C_;
    const u16* Bb = Bt + (size_t)bn * C_;

    auto stage = [&](int bf, int kt) {
        const int k0 = kt * 64;
        #pragma unroll
        for (int t = 0; t < 4; ++t)
            gl2lds16(Ab + (size_t)(w * 32 + t * 8 + sr8) * C_ + k0 + scol,
                     (char*)As + bf * 16384 + (w * 32 + t * 8) * 128);
        #pragma unroll
        for (int t = 0; t < 2; ++t)
            gl2lds16(Bb + (size_t)(w * 16 + t * 8 + sr8) * C_ + k0 + scol,
                     (char*)Bs + bf * 8192 + (w * 16 + t * 8) * 128);
    };

    stage(0, 0);
    for (int kt = 0; kt < 8; ++kt) {
        __syncthreads();
        const int bf = kt & 1;
        if (kt < 7) stage(bf ^ 1, kt + 1);
        #pragma unroll
        for (int kk = 0; kk < 2; ++kk) {
            const int pc = ((kk * 4 + q4) ^ (l16 & 7)) * 8;  // phys chunk (u16)
            s8v a[4], b[2];
            #pragma unroll
            for (int i = 0; i < 4; ++i)
                a[i] = *(const s8v*)&As[bf][wr * 64 + i * 16 + l16][pc];
            #pragma unroll
            for (int j = 0; j < 2; ++j)
                b[j] = *(const s8v*)&Bs[bf][wc * 32 + j * 16 + l16][pc];
            #pragma unroll
            for (int i = 0; i < 4; ++i)
                #pragma unroll
                for (int j = 0; j < 2; ++j)
                    acc[i][j] = __builtin_amdgcn_mfma_f32_16x16x32_bf16(a[i], b[j], acc[i][j], 0, 0, 0);
        }
    }

    #pragma unroll
    for (int j = 0; j < 2; ++j) {
        const int n = bn + wc * 32 + j * 16 + l16;
        const float bj = bias ? bias[n] : 0.0f;
        #pragma unroll
        for (int i = 0; i < 4; ++i) {
            const int m = bm + wr * 64 + i * 16 + q4 * 4;
            #pragma unroll
            for (int reg = 0; reg < 4; ++reg) {
                const float vv = acc[i][j][reg] + bj;
                if constexpr (OB) ((u16*)outv)[(size_t)(m + reg) * C_ + n] = f2b(vv);
                else              ((float*)outv)[(size_t)(m + reg) * C_ + n] = vv;
            }
        }
    }
}

// ---------------------------------------------------------------------------
// Fused QKV projection, 128x64 tiles, grid (64, 24) = 1536 blocks.
// which = blockIdx.y>>3 selects {Wq,Wk,Wv}. K written with k-group XOR
// swizzle; V written TRANSPOSED + XOR-swizzled into Vt[b,h,d,s].
// ---------------------------------------------------------------------------
__global__ __launch_bounds__(256) void qkv_k(const u16* __restrict__ A,
                                             const u16* __restrict__ Wq,
                                             const u16* __restrict__ Wk,
                                             const u16* __restrict__ Wv,
                                             u16* __restrict__ oq,
                                             u16* __restrict__ ok,
                                             u16* __restrict__ ovt)
{
    __shared__ u16 As[2][128][64];
    __shared__ u16 Bs[2][64][64];
    const int tid = threadIdx.x;
    const int lane = tid & 63, w = tid >> 6;
    const int q4 = lane >> 4, l16 = lane & 15;
    const int wr = w >> 1, wc = w & 1;
    const int nt = blockIdx.y, which = nt >> 3;
    const u16* Bt = which == 0 ? Wq : (which == 1 ? Wk : Wv);
    const int bm = blockIdx.x * 128, bn = (nt & 7) * 64;
    const int sr8  = lane >> 3;
    const int scol = ((lane & 7) ^ sr8) * 8;

    f4v acc[4][2];
    #pragma unroll
    for (int i = 0; i < 4; ++i)
        #pragma unroll
        for (int j = 0; j < 2; ++j) acc[i][j] = (f4v){0.f, 0.f, 0.f, 0.f};

    const u16* Ab = A  + (size_t)bm * C_;
    const u16* Bb = Bt + (size_t)bn * C_;

    auto stage = [&](int bf, int kt) {
        const int k0 = kt * 64;
        #pragma unroll
        for (int t = 0; t < 4; ++t)
            gl2lds16(Ab + (size_t)(w * 32 + t * 8 + sr8) * C_ + k0 + scol,
                     (char*)As + bf * 16384 + (w * 32 + t * 8) * 128);
        #pragma unroll
        for (int t = 0; t < 2; ++t)
            gl2lds16(Bb + (size_t)(w * 16 + t * 8 + sr8) * C_ + k0 + scol,
                     (char*)Bs + bf * 8192 + (w * 16 + t * 8) * 128);
    };

    stage(0, 0);
    for (int kt = 0; kt < 8; ++kt) {
        __syncthreads();
        const int bf = kt & 1;
        if (kt < 7) stage(bf ^ 1, kt + 1);
        #pragma unroll
        for (int kk = 0; kk < 2; ++kk) {
            const int pc = ((kk * 4 + q4) ^ (l16 & 7)) * 8;
            s8v a[4], b[2];
            #pragma unroll
            for (int i = 0; i < 4; ++i)
                a[i] = *(const s8v*)&As[bf][wr * 64 + i * 16 + l16][pc];
            #pragma unroll
            for (int j = 0; j < 2; ++j)
                b[j] = *(const s8v*)&Bs[bf][wc * 32 + j * 16 + l16][pc];
            #pragma unroll
            for (int i = 0; i < 4; ++i)
                #pragma unroll
                for (int j = 0; j < 2; ++j)
                    acc[i][j] = __builtin_amdgcn_mfma_f32_16x16x32_bf16(a[i], b[j], acc[i][j], 0, 0, 0);
        }
    }

    if (which == 0) {
        #pragma unroll
        for (int j = 0; j < 2; ++j) {
            const int n = bn + wc * 32 + j * 16 + l16;
            #pragma unroll
            for (int i = 0; i < 4; ++i) {
                const int m = bm + wr * 64 + i * 16 + q4 * 4;
                #pragma unroll
                for (int reg = 0; reg < 4; ++reg)
                    oq[(size_t)(m + reg) * C_ + n] = f2b(acc[i][j][reg]);
            }
        }
    } else if (which == 1) {
        #pragma unroll
        for (int j = 0; j < 2; ++j) {
            const int n = bn + wc * 32 + j * 16 + l16;
            const int nswz = (n & ~31) | ((((n >> 3) & 3) ^ q4) << 3) | (n & 7);
            #pragma unroll
            for (int i = 0; i < 4; ++i) {
                const int m = bm + wr * 64 + i * 16 + q4 * 4;
                #pragma unroll
                for (int reg = 0; reg < 4; ++reg)
                    ok[(size_t)(m + reg) * C_ + nswz] = f2b(acc[i][j][reg]);
            }
        }
    } else {
        const int bglob = bm >> 11;
        const int sbase = bm & (S_ - 1);
        #pragma unroll
        for (int j = 0; j < 2; ++j) {
            const int n = bn + wc * 32 + j * 16 + l16;
            const int h = n >> 6, d = n & 63;
            u16* vrow = ovt + ((size_t)(bglob * H_ + h) * D_ + d) * S_;
            const int xw = d & 7;
            #pragma unroll
            for (int i = 0; i < 4; ++i) {
                const int s = sbase + wr * 64 + i * 16 + q4 * 4;
                const int pg = ((s & 31) >> 2) ^ xw;
                s4v pv;
                #pragma unroll
                for (int reg = 0; reg < 4; ++reg) pv[reg] = (short)f2b(acc[i][j][reg]);
                *(s4v*)&vrow[(s & ~31) + (pg << 2)] = pv;
            }
        }
    }
}

// ---------------------------------------------------------------------------
// bf16-chain LayerNorm kernels. One wave per row, 4 rows/block.
// ---------------------------------------------------------------------------
__global__ __launch_bounds__(256) void ln2xb_k(const u16* __restrict__ in,
                                               const float* __restrict__ res,
                                               const float* __restrict__ w1,
                                               const float* __restrict__ b1,
                                               const float* __restrict__ w2,
                                               const float* __restrict__ b2,
                                               u16* __restrict__ out1,
                                               u16* __restrict__ out2)
{
    const int lane = threadIdx.x & 63;
    const int row  = blockIdx.x * 4 + (threadIdx.x >> 6);
    const size_t off = (size_t)row * C_ + lane * 8;
    float v[8];
    b2f8(*(const s8v*)&in[off], v);
    {
        const float4 r0 = *(const float4*)&res[off];
        const float4 r1 = *(const float4*)&res[off + 4];
        v[0] += r0.x; v[1] += r0.y; v[2] += r0.z; v[3] += r0.w;
        v[4] += r1.x; v[5] += r1.y; v[6] += r1.z; v[7] += r1.w;
    }
    float s = 0.f, ss = 0.f;
    #pragma unroll
    for (int k = 0; k < 8; ++k) { s += v[k]; ss += v[k] * v[k]; }
    #pragma unroll
    for (int o = 32; o >= 1; o >>= 1) { s += __shfl_xor(s, o); ss += __shfl_xor(ss, o); }
    float mean = s * (1.0f / C_);
    float rstd = rsqrtf(ss * (1.0f / C_) - mean * mean + 1e-5f);

    const float4 wA0 = *(const float4*)&w1[lane * 8];
    const float4 wA1 = *(const float4*)&w1[lane * 8 + 4];
    const float4 bA0 = *(const float4*)&b1[lane * 8];
    const float4 bA1 = *(const float4*)&b1[lane * 8 + 4];
    const float wA[8] = {wA0.x, wA0.y, wA0.z, wA0.w, wA1.x, wA1.y, wA1.z, wA1.w};
    const float bA[8] = {bA0.x, bA0.y, bA0.z, bA0.w, bA1.x, bA1.y, bA1.z, bA1.w};
    float y[8];
    s8v o1;
    #pragma unroll
    for (int k = 0; k < 8; ++k) {
        y[k] = (v[k] - mean) * rstd * wA[k] + bA[k];
        o1[k] = (short)f2b(y[k]);
    }
    *(s8v*)&out1[off] = o1;

    s = 0.f; ss = 0.f;
    #pragma unroll
    for (int k = 0; k < 8; ++k) { s += y[k]; ss += y[k] * y[k]; }
    #pragma unroll
    for (int o = 32; o >= 1; o >>= 1) { s += __shfl_xor(s, o); ss += __shfl_xor(ss, o); }
    mean = s * (1.0f / C_);
    rstd = rsqrtf(ss * (1.0f / C_) - mean * mean + 1e-5f);

    const float4 wB0 = *(const float4*)&w2[lane * 8];
    const float4 wB1 = *(const float4*)&w2[lane * 8 + 4];
    const float4 bB0 = *(const float4*)&b2[lane * 8];
    const float4 bB1 = *(const float4*)&b2[lane * 8 + 4];
    const float wB[8] = {wB0.x, wB0.y, wB0.z, wB0.w, wB1.x, wB1.y, wB1.z, wB1.w};
    const float bB[8] = {bB0.x, bB0.y, bB0.z, bB0.w, bB1.x, bB1.y, bB1.z, bB1.w};
    s8v o2;
    #pragma unroll
    for (int k = 0; k < 8; ++k)
        o2[k] = (short)f2b((y[k] - mean) * rstd * wB[k] + bB[k]);
    *(s8v*)&out2[off] = o2;
}

__global__ __launch_bounds__(256) void lnb_k(const u16* __restrict__ in,
                                             const float* __restrict__ w,
                                             const float* __restrict__ bb,
                                             u16* __restrict__ out)
{
    const int lane = threadIdx.x & 63;
    const int row  = blockIdx.x * 4 + (threadIdx.x >> 6);
    const size_t off = (size_t)row * C_ + lane * 8;
    float v[8];
    b2f8(*(const s8v*)&in[off], v);
    float s = 0.f, ss = 0.f;
    #pragma unroll
    for (int k = 0; k < 8; ++k) { s += v[k]; ss += v[k] * v[k]; }
    #pragma unroll
    for (int o = 32; o >= 1; o >>= 1) { s += __shfl_xor(s, o); ss += __shfl_xor(ss, o); }
    const float mean = s * (1.0f / C_);
    const float rstd = rsqrtf(ss * (1.0f / C_) - mean * mean + 1e-5f);
    const float4 w0 = *(const float4*)&w[lane * 8];
    const float4 w1 = *(const float4*)&w[lane * 8 + 4];
    const float4 b0 = *(const float4*)&bb[lane * 8];
    const float4 b1 = *(const float4*)&bb[lane * 8 + 4];
    const float wv[8] = {w0.x, w0.y, w0.z, w0.w, w1.x, w1.y, w1.z, w1.w};
    const float bv[8] = {b0.x, b0.y, b0.z, b0.w, b1.x, b1.y, b1.z, b1.w};
    s8v o;
    #pragma unroll
    for (int k = 0; k < 8; ++k)
        o[k] = (short)f2b((v[k] - mean) * rstd * wv[k] + bv[k]);
    *(s8v*)&out[off] = o;
}

__global__ __launch_bounds__(256) void lnfin_k(const u16* __restrict__ in,
                                               const u16* __restrict__ res,
                                               const float* __restrict__ w,
                                               const float* __restrict__ bb,
                                               float* __restrict__ out)
{
    const int lane = threadIdx.x & 63;
    const int row  = blockIdx.x * 4 + (threadIdx.x >> 6);
    const size_t off = (size_t)row * C_ + lane * 8;
    float v[8], r[8];
    b2f8(*(const s8v*)&in[off], v);
    b2f8(*(const s8v*)&res[off], r);
    #pragma unroll
    for (int k = 0; k < 8; ++k) v[k] += r[k];
    float s = 0.f, ss = 0.f;
    #pragma unroll
    for (int k = 0; k < 8; ++k) { s += v[k]; ss += v[k] * v[k]; }
    #pragma unroll
    for (int o = 32; o >= 1; o >>= 1) { s += __shfl_xor(s, o); ss += __shfl_xor(ss, o); }
    const float mean = s * (1.0f / C_);
    const float rstd = rsqrtf(ss * (1.0f / C_) - mean * mean + 1e-5f);
    const float4 w0 = *(const float4*)&w[lane * 8];
    const float4 w1 = *(const float4*)&w[lane * 8 + 4];
    const float4 b0 = *(const float4*)&bb[lane * 8];
    const float4 b1 = *(const float4*)&bb[lane * 8 + 4];
    const float wv[8] = {w0.x, w0.y, w0.z, w0.w, w1.x, w1.y, w1.z, w1.w};
    const float bv[8] = {b0.x, b0.y, b0.z, b0.w, b1.x, b1.y, b1.z, b1.w};
    float4 o0, o1;
    o0.x = (v[0] - mean) * rstd * wv[0] + bv[0];
    o0.y = (v[1] - mean) * rstd * wv[1] + bv[1];
    o0.z = (v[2] - mean) * rstd * wv[2] + bv[2];
    o0.w = (v[3] - mean) * rstd * wv[3] + bv[3];
    o1.x = (v[4] - mean) * rstd * wv[4] + bv[4];
    o1.y = (v[5] - mean) * rstd * wv[5] + bv[5];
    o1.z = (v[6] - mean) * rstd * wv[6] + bv[6];
    o1.w = (v[7] - mean) * rstd * wv[7] + bv[7];
    *(float4*)&out[off]     = o0;
    *(float4*)&out[off + 4] = o1;
}

// ---------------------------------------------------------------------------
// Causal flash attention, register-resident P. grid (16,H,B), 256 thr.
// COMPLEMENTARY-PAIR BALANCING: each block runs q-tile (31-bx) then q-tile
// (bx) -> uniform 33 KV-iterations per block, no tail imbalance (the old
// 32-block LPT grid was fully co-resident, so heavy blocks pinned duration
// at 32 iters while light blocks drained idle). Pass-0 writeout overlaps
// pass-1's initial K/V staging. Per-tile pipeline (swizzles, constant-max
// softmax, register-resident P) unchanged. setprio(1) wraps MFMA clusters.
// ---------------------------------------------------------------------------
__global__ __launch_bounds__(256) void attn_k(const u16* __restrict__ Q,
                                              const u16* __restrict__ K,
                                              const u16* __restrict__ Vt,
                                              u16* __restrict__ O)
{
    __shared__ u16 Ks[2][2][64][32];   // [buf][kh][key][k32] (k-group swizzled)
    __shared__ u16 Vs[2][2][64][32];   // [buf][keyhalf][d][key32] (swizzled)
    const int tid = threadIdx.x;
    const int lane = tid & 63, w = tid >> 6;
    const int q4 = lane >> 4, l16 = lane & 15;
    const int h = blockIdx.y, b = blockIdx.z;
    const size_t base  = ((size_t)b * S_) * C_ + h * D_;
    const size_t basev = ((size_t)(b * H_ + h)) * D_ * S_;
    const int lr = lane >> 2, lc = (lane & 3) * 8;
    const int kq = (q4 ^ ((l16 >> 2) & 3)) * 8;   // undo K k-group swizzle
    const int qrow = w * 16 + l16;

    // per-wave staging pointers: row = w*16+lr, kh halves at +0/+32
    const u16* kbase = K  + base  + (size_t)(w * 16 + lr) * C_ + lc;
    const u16* vbase = Vt + basev + (size_t)(w * 16 + lr) * S_ + lc;
    char* kd0 = (char*)Ks + w * 1024;
    char* kd1 = (char*)Ks + (4 + w) * 1024;
    char* vd0 = (char*)Vs + w * 1024;
    char* vd1 = (char*)Vs + (4 + w) * 1024;

    f4v o[4];
    float lp[4];
    s8v qf[2];

    auto stage0 = [&]() {                 // kv tile 0 -> buffer 0
        gl2lds16(kbase,      kd0);
        gl2lds16(kbase + 32, kd1);
        gl2lds16(vbase,      vd0);
        gl2lds16(vbase + 32, vd1);
    };
    auto loadq = [&](int qb) {
        #pragma unroll
        for (int kh = 0; kh < 2; ++kh)
            qf[kh] = *(const s8v*)&Q[base + (size_t)(qb * 64 + qrow) * C_ + kh * 32 + q4 * 8];
        #pragma unroll
        for (int j = 0; j < 4; ++j) { o[j] = (f4v){0.f, 0.f, 0.f, 0.f}; lp[j] = 0.f; }
    };

    auto kbloop = [&](int qb) {
        const u16* kp = kbase + 64 * C_;
        const u16* vp = vbase + 64;
        for (int kb = 0; kb <= qb; ++kb) {
            __syncthreads();
            const int buf = kb & 1;
            if (kb < qb) {
                const int nb = (buf ^ 1) * 8192;
                gl2lds16(kp,      kd0 + nb);
                gl2lds16(kp + 32, kd1 + nb);
                gl2lds16(vp,      vd0 + nb);
                gl2lds16(vp + 32, vd1 + nb);
                kp += 64 * C_;
                vp += 64;
            }

            f4v sc[4];
            #pragma unroll
            for (int j = 0; j < 4; ++j) sc[j] = (f4v){0.f, 0.f, 0.f, 0.f};
            __builtin_amdgcn_s_setprio(1);
            #pragma unroll
            for (int kh = 0; kh < 2; ++kh) {
                #pragma unroll
                for (int j = 0; j < 4; ++j) {
                    const s8v kf = *(const s8v*)&Ks[buf][kh][j * 16 + l16][kq];
                    sc[j] = __builtin_amdgcn_mfma_f32_16x16x32_bf16(kf, qf[kh], sc[j], 0, 0, 0);
                }
            }
            __builtin_amdgcn_s_setprio(0);

            s4v pa[4];
            if (kb == qb) {      // diagonal tile: masked path
                #pragma unroll
                for (int j = 0; j < 4; ++j) {
                    float ps = 0.0f;
                    #pragma unroll
                    for (int reg = 0; reg < 4; ++reg) {
                        float t = fmaf(sc[j][reg], 0.18033688011112043f, -11.541560327111707f);
                        if ((j * 16 + q4 * 4 + reg) > qrow) t = -128.0f;
                        const float p = exp2f(t);
                        ps += p;
                        pa[j][reg] = (short)(__builtin_bit_cast(u32, p) >> 16);
                    }
                    lp[j] += ps;
                }
            } else {             // interior tile: no mask VALU
                #pragma unroll
                for (int j = 0; j < 4; ++j) {
                    float ps = 0.0f;
                    #pragma unroll
                    for (int reg = 0; reg < 4; ++reg) {
                        const float p = exp2f(fmaf(sc[j][reg], 0.18033688011112043f,
                                                   -11.541560327111707f));
                        ps += p;
                        pa[j][reg] = (short)(__builtin_bit_cast(u32, p) >> 16);
                    }
                    lp[j] += ps;
                }
            }

            __builtin_amdgcn_s_setprio(1);
            #pragma unroll
            for (int c = 0; c < 4; ++c) {
                const int gh = (((c & 1) * 4 + q4) ^ (l16 & 7)) * 4;
                #pragma unroll
                for (int dj = 0; dj < 4; ++dj) {
                    const s4v vb = *(const s4v*)&Vs[buf][c >> 1][dj * 16 + l16][gh];
                    o[dj] = __builtin_amdgcn_mfma_f32_16x16x16bf16_1k(pa[c], vb, o[dj], 0, 0, 0);
                }
            }
            __builtin_amdgcn_s_setprio(0);
        }
    };

    auto writeout = [&](int qb) {
        float lt = (lp[0] + lp[1]) + (lp[2] + lp[3]);
        lt += __shfl_xor(lt, 16);
        lt += __shfl_xor(lt, 32);
        #pragma unroll
        for (int reg = 0; reg < 4; ++reg) {
            const float inv = 1.0f / __shfl(lt, q4 * 4 + reg);
            const size_t rowoff = base + (size_t)(qb * 64 + w * 16 + q4 * 4 + reg) * C_;
            #pragma unroll
            for (int dj = 0; dj < 4; ++dj)
                O[rowoff + dj * 16 + l16] = f2b(o[dj][reg] * inv);
        }
    };

    // ---- pass 0: heavy q-tile
    int qb = 31 - (int)blockIdx.x;
    stage0();
    loadq(qb);
    kbloop(qb);
    // ---- boundary: all LDS reads done -> restage tile 0, overlap writeout
    __syncthreads();
    stage0();
    writeout(qb);
    // ---- pass 1: light q-tile
    const int qb1 = (int)blockIdx.x;
    loadq(qb1);
    kbloop(qb1);
    writeout(qb1);
}

// ---------------------------------------------------------------------------
extern "C" void kernel_launch(void* const* d_in, const int* in_sizes, int n_in,
                              void* d_out, int out_size, void* d_ws, size_t ws_size,
                              hipStream_t stream)
{
    const float* x       = (const float*)d_in[0];
    const float* Wq      = (const float*)d_in[1];
    const float* Wk      = (const float*)d_in[2];
    const float* Wv      = (const float*)d_in[3];
    const float* Wo      = (const float*)d_in[4];
    const float* ln1_w   = (const float*)d_in[5];
    const float* ln1_b   = (const float*)d_in[6];
    const float* ffln1_w = (const float*)d_in[7];
    const float* ffln1_b = (const float*)d_in[8];
    const float* ff_w1   = (const float*)d_in[9];
    const float* ff_b1   = (const float*)d_in[10];
    const float* ffln2_w = (const float*)d_in[11];
    const float* ffln2_b = (const float*)d_in[12];
    const float* ff_w2   = (const float*)d_in[13];
    const float* ff_b2   = (const float*)d_in[14];
    const float* ln2_w   = (const float*)d_in[15];
    const float* ln2_b   = (const float*)d_in[16];
    float* out = (float*)d_out;

    const size_t MC = (size_t)M_ * C_;   // 4,194,304
    const size_t WW = (size_t)C_ * C_;
    u16* xb   = (u16*)d_ws;
    u16* WqT  = xb + MC;
    u16* WkT  = WqT + WW;
    u16* WvT  = WkT + WW;
    u16* WoT  = WvT + WW;
    u16* W1T  = WoT + WW;
    u16* W2T  = W1T + WW;
    u16* qbuf = W2T + WW;
    u16* kbuf = qbuf + MC;
    u16* vbuf = kbuf + MC;
    u16* vtbuf= vbuf + MC;
    u16*  abuf = xb;       // attn out; xb dead after qkv_k
    u16*  tf   = qbuf;     // bf16 chain intermediate (qbuf dead after attn)
    u16*  xln  = vbuf;     // bf16 x_ln (vbuf spare)

    const dim3 gg(M_ / 128, C_ / 64);    // (64, 8) = 512 gemm blocks
    const dim3 gq(M_ / 128, 24);         // fused QKV, 1536 blocks
    const dim3 ga(16, H_, B_);           // 512 attn blocks, uniform 33 iters
    const int  gl = M_ / 4;

    prep_k<<<5632, 256, 0, stream>>>(x, xb, Wq, Wk, Wv, Wo, ff_w1, ff_w2,
                                     WqT, WkT, WvT, WoT, W1T, W2T);

    qkv_k<<<gq, 256, 0, stream>>>(xb, WqT, WkT, WvT, qbuf, kbuf, vtbuf);
    attn_k<<<ga, 256, 0, stream>>>(qbuf, kbuf, vtbuf, abuf);

    // t = a@Wo (bf16); xln = LN(t+x, ln1) bf16; xb = LN(xln, ffln1) bf16
    gemm_k<true><<<gg, 256, 0, stream>>>(abuf, WoT, nullptr, tf);
    ln2xb_k<<<gl, 256, 0, stream>>>(tf, x, ln1_w, ln1_b, ffln1_w, ffln1_b,
                                    xln, xb);
    // h1 = xb@W1 + b1 (bf16); xb = LN(h1, ffln2) bf16
    gemm_k<true><<<gg, 256, 0, stream>>>(xb, W1T, ff_b1, tf);
    lnb_k<<<gl, 256, 0, stream>>>(tf, ffln2_w, ffln2_b, xb);
    // h2 = xb@W2 + b2 (bf16); out = LN(h2 + xln, ln2) fp32
    gemm_k<true><<<gg, 256, 0, stream>>>(xb, W2T, ff_b2, tf);
    lnfin_k<<<gl, 256, 0, stream>>>(tf, xln, ln2_w, ln2_b, out);
}